// Round 12
// baseline (120.895 us; speedup 1.0000x reference)
//
#include <hip/hip_runtime.h>
#include <hip/hip_bf16.h>

#define NREPS   16
#define NELEMS  128
#define DD      32
#define MATSZ   (DD * DD)        // 1024 elements per 32x32 block
#define EMB     (NREPS * MATSZ)  // 16384

typedef __attribute__((ext_vector_type(8))) short bf16x8;  // 8 bf16 = 4 VGPR
typedef __attribute__((ext_vector_type(4))) float f32x4;   // MFMA C/D frag

static __device__ __forceinline__ short f2bf(float f) {
    __hip_bfloat16 h = __float2bfloat16(f);   // RTN
    return *reinterpret_cast<short*>(&h);
}

// ---- Prep: Mt[mat][col][k] = bf16( reps[mat][k][col] / (||.||_F + 1e-6) ) ----
// One block per (r,e) matrix. Coalesced 4KB read, padded-LDS transpose,
// coalesced 2KB bf16 write. Norm + transpose leave the hot path entirely;
// the 4MB bf16 table fits a per-XCD L2.
__global__ __launch_bounds__(256) void prep_kernel(
    const float* __restrict__ reps, ushort* __restrict__ Mt)
{
    __shared__ float lM[DD * 33];          // +1 pad: transpose reads 2-way max
    __shared__ float red[4];
    const int mat = blockIdx.x;            // r*128 + e
    const int t   = threadIdx.x;           // 0..255

    float4 v = reinterpret_cast<const float4*>(reps + (size_t)mat * MATSZ)[t];
    const int i  = t >> 3;                 // row
    const int c0 = (t & 7) << 2;           // col base
    lM[i * 33 + c0 + 0] = v.x;
    lM[i * 33 + c0 + 1] = v.y;
    lM[i * 33 + c0 + 2] = v.z;
    lM[i * 33 + c0 + 3] = v.w;

    float s = v.x * v.x + v.y * v.y + v.z * v.z + v.w * v.w;
    #pragma unroll
    for (int off = 32; off; off >>= 1) s += __shfl_xor(s, off, 64);
    if ((t & 63) == 0) red[t >> 6] = s;
    __syncthreads();
    const float scale = 1.0f / (sqrtf(red[0] + red[1] + red[2] + red[3]) + 1e-6f);

    // thread t writes transposed elements q = t*4..t*4+3 (q = col*32 + k)
    const int col = t >> 3;
    const int k0  = (t & 7) << 2;
    ushort4 o;
    o.x = (ushort)f2bf(lM[(k0 + 0) * 33 + col] * scale);
    o.y = (ushort)f2bf(lM[(k0 + 1) * 33 + col] * scale);
    o.z = (ushort)f2bf(lM[(k0 + 2) * 33 + col] * scale);
    o.w = (ushort)f2bf(lM[(k0 + 3) * 33 + col] * scale);
    reinterpret_cast<ushort4*>(Mt + (size_t)mat * MATSZ)[t] = o;
}

// One item = one (b, r) 32x32 matmul: 4 A-dwordx4 + 2 Mt-dwordx4 loads,
// bf16 convert, 4x mfma_f32_16x16x32_bf16, 16 scalar nt stores (R8 pattern:
// proven WRITE amplification 1.04x and L3 retention of emb).
struct RegSet {
    float4 alo[2], ahi[2];
    bf16x8 mt[2];
};

static __device__ __forceinline__ void issue_loads(
    RegSet& s, const float* __restrict__ A, const ushort* __restrict__ M,
    int lr, int k0)
{
    #pragma unroll
    for (int ti = 0; ti < 2; ++ti) {
        const float* ap = A + (ti * 16 + lr) * DD + k0;
        s.alo[ti] = *reinterpret_cast<const float4*>(ap);
        s.ahi[ti] = *reinterpret_cast<const float4*>(ap + 4);
    }
    #pragma unroll
    for (int tj = 0; tj < 2; ++tj)
        s.mt[tj] = *reinterpret_cast<const bf16x8*>(M + (tj * 16 + lr) * DD + k0);
}

static __device__ __forceinline__ void compute_store(
    const RegSet& s, float* __restrict__ Ob, int lr, int row0)
{
    bf16x8 af[2];
    #pragma unroll
    for (int ti = 0; ti < 2; ++ti) {
        bf16x8 f;
        f[0] = f2bf(s.alo[ti].x); f[1] = f2bf(s.alo[ti].y);
        f[2] = f2bf(s.alo[ti].z); f[3] = f2bf(s.alo[ti].w);
        f[4] = f2bf(s.ahi[ti].x); f[5] = f2bf(s.ahi[ti].y);
        f[6] = f2bf(s.ahi[ti].z); f[7] = f2bf(s.ahi[ti].w);
        af[ti] = f;
    }
    const f32x4 z = {0.0f, 0.0f, 0.0f, 0.0f};
    f32x4 acc[2][2];
    #pragma unroll
    for (int ti = 0; ti < 2; ++ti)
        #pragma unroll
        for (int tj = 0; tj < 2; ++tj)
            acc[ti][tj] = __builtin_amdgcn_mfma_f32_16x16x32_bf16(
                af[ti], s.mt[tj], z, 0, 0, 0);
    #pragma unroll
    for (int ti = 0; ti < 2; ++ti)
        #pragma unroll
        for (int m = 0; m < 4; ++m) {
            const int row = ti * 16 + row0 + m;
            #pragma unroll
            for (int tj = 0; tj < 2; ++tj)
                __builtin_nontemporal_store(acc[ti][tj][m],
                                            Ob + row * DD + tj * 16 + lr);
        }
}

// ---- Main: persistent-ish blocks with a cross-item register pipeline.
// Grid = B/2 (2048 blocks = 8/CU, 4x fewer dispatches than R8). Each wave w
// owns 8 items: reps 4w..4w+3 of batches b0 and b0+1. Explicit ping-pong
// (s0/s1, all compile-time indexed): while item i is converted/MFMA'd/stored,
// item i+1's 6 loads are in flight -- load-to-use distance is a full
// compute+store phase. This is the structural fix for the MLP that R9/R11's
// source-order hoist + sched_barrier failed to deliver (VGPR stayed 36-44).
// A-frag: lane holds A[ti*16+(l&15)][(l>>4)*8..+7]; Mt-frag from the bf16
// normalized transposed table (L2-resident). C (m89): row=(l>>4)*4+m, col=l&15.
__global__ __launch_bounds__(256) void trans_mfma_pipe_kernel(
    const float*  __restrict__ emb,    // [B][16384] fp32
    const int*    __restrict__ syms,   // [B]
    const ushort* __restrict__ Mt,     // [2048][32][32] bf16 (normalized, T)
    const int*    __restrict__ trans,  // [64]
    float*        __restrict__ out)    // [B][16384]
{
    const int b0 = blockIdx.x << 1;
    const int w  = threadIdx.x >> 6;       // wave 0..3
    const int l  = threadIdx.x & 63;
    const int lr   = l & 15;               // row (A) / col (B,C) within tile
    const int k0   = (l >> 4) << 3;        // k base {0,8,16,24}
    const int row0 = (l >> 4) << 2;        // C row base

    const int e0 = trans[syms[b0]];
    const int e1 = trans[syms[b0 + 1]];

    // item i (0..7): batch b0+(i>>2), rep (w<<2)+(i&3), symbol-element e0/e1
    auto Aptr = [&](int i) {
        return emb + (size_t)(b0 + (i >> 2)) * EMB
                   + (size_t)((w << 2) + (i & 3)) * MATSZ;
    };
    auto Mptr = [&](int i) {
        return Mt + ((size_t)((w << 2) + (i & 3)) * NELEMS
                     + ((i >> 2) ? e1 : e0)) * MATSZ;
    };
    auto Optr = [&](int i) {
        return out + (size_t)(b0 + (i >> 2)) * EMB
                   + (size_t)((w << 2) + (i & 3)) * MATSZ;
    };

    RegSet s0, s1;
    issue_loads(s0, Aptr(0), Mptr(0), lr, k0);

    #pragma unroll
    for (int it = 0; it < 8; it += 2) {
        issue_loads(s1, Aptr(it + 1), Mptr(it + 1), lr, k0);
        compute_store(s0, Optr(it), lr, row0);
        if (it + 2 < 8)
            issue_loads(s0, Aptr(it + 2), Mptr(it + 2), lr, k0);
        compute_store(s1, Optr(it + 1), lr, row0);
    }
}

extern "C" void kernel_launch(void* const* d_in, const int* in_sizes, int n_in,
                              void* d_out, int out_size, void* d_ws, size_t ws_size,
                              hipStream_t stream) {
    const float* emb   = (const float*)d_in[0];
    const int*   syms  = (const int*)d_in[1];
    const float* reps  = (const float*)d_in[2];
    const int*   trans = (const int*)d_in[3];
    float*  outp = (float*)d_out;
    ushort* Mt   = (ushort*)d_ws;          // 2048 * 2KB = 4 MB scratch

    const int B = in_sizes[1];             // batch count (4096)

    hipLaunchKernelGGL(prep_kernel, dim3(NREPS * NELEMS), dim3(256), 0, stream,
                       reps, Mt);
    hipLaunchKernelGGL(trans_mfma_pipe_kernel, dim3(B / 2), dim3(256), 0, stream,
                       emb, syms, Mt, trans, outp);
}

// Round 13
// 111.104 us; speedup vs baseline: 1.0881x; 1.0881x over previous
//
#include <hip/hip_runtime.h>
#include <hip/hip_bf16.h>

#define NREPS   16
#define NELEMS  128
#define DD      32
#define MATSZ   (DD * DD)        // 1024 elements per 32x32 block
#define EMB     (NREPS * MATSZ)  // 16384

typedef __attribute__((ext_vector_type(8))) short bf16x8;  // 8 bf16 = 4 VGPR
typedef __attribute__((ext_vector_type(4))) float f32x4;   // MFMA C/D frag

typedef __attribute__((address_space(3))) void lds_void;
typedef __attribute__((address_space(1))) void glb_void;

static __device__ __forceinline__ short f2bf(float f) {
    __hip_bfloat16 h = __float2bfloat16(f);   // RTN
    return *reinterpret_cast<short*>(&h);
}

// Async global->LDS DMA, 16B per lane, dest = wave-uniform base + lane*16.
// No VGPR destination => the scheduler CANNOT sink it (the fix for R9/R11/R12
// where VGPR-load hoisting was silently undone). vmcnt-tracked.
static __device__ __forceinline__ void gload16(const void* g, void* l) {
    __builtin_amdgcn_global_load_lds((glb_void*)g, (lds_void*)l, 16, 0, 0);
}

// ---- Prep: Mt[mat][col][k] = bf16( reps[mat][k][col] / (||.||_F + 1e-6) ) ----
__global__ __launch_bounds__(256) void prep_kernel(
    const float* __restrict__ reps, ushort* __restrict__ Mt)
{
    __shared__ float lM[DD * 33];          // +1 pad: transpose reads 2-way max
    __shared__ float red[4];
    const int mat = blockIdx.x;            // r*128 + e
    const int t   = threadIdx.x;           // 0..255

    float4 v = reinterpret_cast<const float4*>(reps + (size_t)mat * MATSZ)[t];
    const int i  = t >> 3;                 // row
    const int c0 = (t & 7) << 2;           // col base
    lM[i * 33 + c0 + 0] = v.x;
    lM[i * 33 + c0 + 1] = v.y;
    lM[i * 33 + c0 + 2] = v.z;
    lM[i * 33 + c0 + 3] = v.w;

    float s = v.x * v.x + v.y * v.y + v.z * v.z + v.w * v.w;
    #pragma unroll
    for (int off = 32; off; off >>= 1) s += __shfl_xor(s, off, 64);
    if ((t & 63) == 0) red[t >> 6] = s;
    __syncthreads();
    const float scale = 1.0f / (sqrtf(red[0] + red[1] + red[2] + red[3]) + 1e-6f);

    const int col = t >> 3;
    const int k0  = (t & 7) << 2;
    ushort4 o;
    o.x = (ushort)f2bf(lM[(k0 + 0) * 33 + col] * scale);
    o.y = (ushort)f2bf(lM[(k0 + 1) * 33 + col] * scale);
    o.z = (ushort)f2bf(lM[(k0 + 2) * 33 + col] * scale);
    o.w = (ushort)f2bf(lM[(k0 + 3) * 33 + col] * scale);
    reinterpret_cast<ushort4*>(Mt + (size_t)mat * MATSZ)[t] = o;
}

// ---- Main: grid = B, 4 waves/block; wave w owns reps 4w..4w+3 of batch b.
// Double-buffered per-wave LDS slots (2 x 4KB). Pipeline per item p:
//   issue stage(p+1): 4x global_load_lds (16B/lane, fully line-coalesced
//     256B segments) + 2 Mt register loads,
//   s_waitcnt vmcnt(6): everything except the 6 just-issued prefetch ops is
//     complete -> stage(p) landed, stage(p+1) stays in flight under compute,
//   compute(p): 4 swizzled ds_read_b128 -> bf16 -> 4x mfma -> 16 nt stores.
// LDS swizzle (rule 21 pattern: linear DMA dest + inverse-swizzled SOURCE +
// swizzled read): LDS chunk (row, c) holds global chunk (row, c ^ (row&7)),
// achieved by pre-swizzling the per-lane global address; fragment reads at
// chunk c^(lr&7) are then <=2-way bank conflicts (free per m136).
// MFMA + scalar-nt-store epilogue identical to R8 (proven: absmax 7.8e-3,
// write-amp 1.04x, L3 retention of emb).
__global__ __launch_bounds__(256) void trans_dma_kernel(
    const float*  __restrict__ emb,    // [B][16384] fp32
    const int*    __restrict__ syms,   // [B]
    const ushort* __restrict__ Mt,     // [2048][32][32] bf16 (normalized, T)
    const int*    __restrict__ trans,  // [64]
    float*        __restrict__ out)    // [B][16384]
{
    __shared__ float lA[8 * MATSZ];        // 32 KiB: 4 waves x 2 slots x 4KB
    const int b = blockIdx.x;
    const int w = threadIdx.x >> 6;        // wave 0..3
    const int l = threadIdx.x & 63;

    const int lr   = l & 15;               // row (A) / col (Mt,C) within tile
    const int k0   = (l >> 4) << 3;        // k base {0,8,16,24} (floats)
    const int row0 = (l >> 4) << 2;        // C row base
    const int esym = trans[syms[b]];

    const float* Ab    = emb + (size_t)b * EMB + (size_t)(w << 2) * MATSZ;
    float*       lslot = lA + w * 2 * MATSZ;

    // stage matrix p (4KB) into slot s: 4 DMA rounds of 1KB; per-lane source
    // chunk is inverse-swizzled so LDS ends up in the swizzled layout.
    auto stage = [&](int p, int s) {
        const float* Am = Ab + (size_t)p * MATSZ;
        float* ldsb = lslot + s * MATSZ;
        #pragma unroll
        for (int j = 0; j < 4; ++j) {
            const int tp  = j * 64 + l;        // LDS chunk index 0..255
            const int row = tp >> 3;
            const int c   = tp & 7;
            const int gc  = (row << 3) | (c ^ (row & 7));
            gload16(Am + gc * 4, ldsb + j * 256);
        }
    };
    // Mt fragment loads (bf16 normalized transposed table, L2-resident).
    auto loadMt = [&](int p, bf16x8* dst) {
        const ushort* M = Mt + ((size_t)((w << 2) + p) * NELEMS + esym) * MATSZ;
        #pragma unroll
        for (int tj = 0; tj < 2; ++tj)
            dst[tj] = *reinterpret_cast<const bf16x8*>(M + (tj * 16 + lr) * DD + k0);
    };

    bf16x8 mtA[2], mtB[2];
    stage(0, 0);
    loadMt(0, mtA);

    const f32x4 z = {0.0f, 0.0f, 0.0f, 0.0f};
    const int s7  = lr & 7;                // swizzle term
    const int clo = (l >> 4) << 1;         // first chunk of this lane's k-span

    #pragma unroll
    for (int p = 0; p < 4; ++p) {
        if (p < 3) {
            stage(p + 1, (p + 1) & 1);
            if (p & 1) loadMt(p + 1, mtA); else loadMt(p + 1, mtB);
        }
        if (p < 3) asm volatile("s_waitcnt vmcnt(6)" ::: "memory");
        else       asm volatile("s_waitcnt vmcnt(0)" ::: "memory");

        // ---- compute item p from slot p&1 ----
        const float* ldsm = lslot + (p & 1) * MATSZ;
        bf16x8 af[2];
        #pragma unroll
        for (int ti = 0; ti < 2; ++ti) {
            const int row = ti * 16 + lr;
            f32x4 lo = *reinterpret_cast<const f32x4*>(
                ldsm + ((row << 3) | (clo ^ s7)) * 4);
            f32x4 hi = *reinterpret_cast<const f32x4*>(
                ldsm + ((row << 3) | ((clo + 1) ^ s7)) * 4);
            bf16x8 f;
            f[0] = f2bf(lo[0]); f[1] = f2bf(lo[1]);
            f[2] = f2bf(lo[2]); f[3] = f2bf(lo[3]);
            f[4] = f2bf(hi[0]); f[5] = f2bf(hi[1]);
            f[6] = f2bf(hi[2]); f[7] = f2bf(hi[3]);
            af[ti] = f;
        }

        f32x4 acc[2][2];
        #pragma unroll
        for (int ti = 0; ti < 2; ++ti)
            #pragma unroll
            for (int tj = 0; tj < 2; ++tj)
                acc[ti][tj] = __builtin_amdgcn_mfma_f32_16x16x32_bf16(
                    af[ti], (p & 1) ? mtB[tj] : mtA[tj], z, 0, 0, 0);

        float* Ob = out + (size_t)b * EMB + (size_t)((w << 2) + p) * MATSZ;
        #pragma unroll
        for (int ti = 0; ti < 2; ++ti)
            #pragma unroll
            for (int m = 0; m < 4; ++m) {
                const int row = ti * 16 + row0 + m;
                #pragma unroll
                for (int tj = 0; tj < 2; ++tj)
                    __builtin_nontemporal_store(acc[ti][tj][m],
                                                Ob + row * DD + tj * 16 + lr);
            }
    }
}

extern "C" void kernel_launch(void* const* d_in, const int* in_sizes, int n_in,
                              void* d_out, int out_size, void* d_ws, size_t ws_size,
                              hipStream_t stream) {
    const float* emb   = (const float*)d_in[0];
    const int*   syms  = (const int*)d_in[1];
    const float* reps  = (const float*)d_in[2];
    const int*   trans = (const int*)d_in[3];
    float*  outp = (float*)d_out;
    ushort* Mt   = (ushort*)d_ws;          // 2048 * 2KB = 4 MB scratch

    const int B = in_sizes[1];             // batch count (4096)

    hipLaunchKernelGGL(prep_kernel, dim3(NREPS * NELEMS), dim3(256), 0, stream,
                       reps, Mt);
    hipLaunchKernelGGL(trans_dma_kernel, dim3(B), dim3(256), 0, stream,
                       emb, syms, Mt, trans, outp);
}